// Round 10
// baseline (52.798 us; speedup 1.0000x reference)
//
#include <hip/hip_runtime.h>

// HFOnlyAttn MFMA v8 = v7 with X staged via global_load_lds (per-lane gather
// source, linear LDS dest): all 12 dwordx4 staging loads in flight at zero
// VGPR cost, ONE vmcnt(0) wait. X lands as fp32 [192][16] per-wave LDS tile
// (12KB/wave); y-relayout reuses the same region (X dead after convert).
// LDS 48KB/block -> 3 blocks/CU.
// qkv^T = Wqkv^T (192x64) @ X^T (64 x px); 4-head 3x3 softmax in-register;
// y -> per-wave LDS relayout -> proj: out^T = Wproj^T @ y^T; residual from Xf.
// mfma_f32_16x16x32_bf16:  A: lane l -> row=l&15, k=(l>>4)*8+{0..7}
//                          B: lane l -> col=l&15, k=(l>>4)*8+{0..7}
//                          C: lane l -> col=l&15, row=(l>>4)*4+reg
// Residual extraction: channel b*64+m*16+g*4+j of pixel c lives in
// Xf[b][m>>1], element (g&1)*4+j, on lane ((m&1)*2+(g>>1))*16+c.

typedef __attribute__((ext_vector_type(8))) short bf16x8;
typedef __attribute__((ext_vector_type(4))) float f32x4;

constexpr int kHW = 16384;
constexpr int kC = 192;

__device__ __forceinline__ unsigned short f2bf(float f) {
  unsigned int u = __float_as_uint(f);
  return (unsigned short)((u + 0x7fffu + ((u >> 16) & 1u)) >> 16);  // RNE
}

// kernel0: pack Wqkv^T/Wproj^T A-fragments into ws (24 + 8 frags x 1024B).
__global__ void pack_weights(const float* __restrict__ Wqkv,
                             const float* __restrict__ Wproj,
                             unsigned char* __restrict__ wsc) {
  const int tid = threadIdx.x;
  const int wid = tid >> 6;
  const int l = tid & 63;
  const int c = l & 15;
  const int g = l >> 4;
  for (int f = wid; f < 24; f += 4) {
    const int m = f >> 1, s = f & 1;
    const int row = m * 16 + c;
    const int k0 = s * 32 + g * 8;
    bf16x8 wf;
#pragma unroll
    for (int j = 0; j < 8; ++j) wf[j] = (short)f2bf(Wqkv[(k0 + j) * 192 + row]);
    *(bf16x8*)(wsc + f * 1024 + l * 16) = wf;
  }
  for (int f = wid; f < 8; f += 4) {
    const int m = f >> 1, s = f & 1;
    const int row = m * 16 + c;
    const int k0 = s * 32 + g * 8;
    bf16x8 wf;
#pragma unroll
    for (int j = 0; j < 8; ++j) wf[j] = (short)f2bf(Wproj[(k0 + j) * 64 + row]);
    *(bf16x8*)(wsc + 24576 + f * 1024 + l * 16) = wf;
  }
}

__global__ __launch_bounds__(256, 3) void hfattn_mfma8(
    const float* __restrict__ hf,
    const unsigned char* __restrict__ wfr,  // packed weight frags (32KB)
    const float* __restrict__ bproj,
    const float* __restrict__ rscale,
    float* __restrict__ out) {
  // LDS: 12KB per wave. First used as fp32 X tile [192ch][16px]; after
  // conversion to Xf registers, reused as the y-relayout buffer (6KB).
  __shared__ char smem[49152];

  const int tid = threadIdx.x;
  const int wid = tid >> 6;
  const int l = tid & 63;
  const int c = l & 15;  // MFMA col (pixel slot)
  const int g = l >> 4;  // 4-lane group

  char* const wbase = smem + wid * 12288;
  const f32x4 zz = {0.f, 0.f, 0.f, 0.f};
  const bf16x8* const wp = (const bf16x8*)wfr;

  const int pxB = blockIdx.x * 64 + wid * 16;  // 2048 blocks x 64 px
  const int b8 = pxB >> 14;
  const int blkBase = b8 * (kC * kHW);
  const int hw0 = (pxB & (kHW - 1));     // wave's first pixel
  const int hw = hw0 + c;                // this lane's pixel
  const float* __restrict__ hfp = hf + blkBase + hw;
  float* __restrict__ outp = out + blkBase + hw;

  const float rv = rscale[0];

  // ---------- phase 1: X -> LDS via global_load_lds (12 x 1KB, one wait) ----
  // Instr i covers channels i*16..i*16+15: lane l loads float4 = 4 px of
  // channel i*16+(l>>2), px group l&3; HW writes LDS at wbase+i*1024+l*16.
  // Resulting LDS layout: lds32[ch*16 + px].
  {
    const int ch = (l >> 2);            // sub-channel within the 16 of instr i
    const int k4 = (l & 3) * 4;         // pixel group
    const float* src0 = hf + blkBase + ch * kHW + hw0 + k4;
#pragma unroll
    for (int i = 0; i < 12; ++i) {
      __builtin_amdgcn_global_load_lds(
          (const __attribute__((address_space(1))) unsigned int*)(src0 +
                                                                  i * 16 * kHW),
          (__attribute__((address_space(3))) unsigned int*)(wbase + i * 1024),
          16, 0, 0);
    }
  }
  asm volatile("s_waitcnt vmcnt(0)" ::: "memory");
  __builtin_amdgcn_sched_barrier(0);

  // ---------- convert LDS X tile to bf16 B-fragments ----------
  const float* const xs = (const float*)wbase;  // lds32[ch*16+px]
  bf16x8 Xf[3][2];
#pragma unroll
  for (int b = 0; b < 3; ++b)
#pragma unroll
    for (int s = 0; s < 2; ++s) {
      bf16x8 xf;
#pragma unroll
      for (int j = 0; j < 8; ++j)
        xf[j] = (short)f2bf(xs[(b * 64 + s * 32 + g * 8 + j) * 16 + c]);
      Xf[b][s] = xf;
    }

  // ---------- per-head: q,k -> softmax -> v -> y -> LDS (reused region) ----
  char* const yBase = wbase;
#pragma unroll 1
  for (int h = 0; h < 4; ++h) {
    const bf16x8 qA0 = wp[(h * 2 + 0) * 64 + l];
    const bf16x8 qA1 = wp[(h * 2 + 1) * 64 + l];
    const bf16x8 kA0 = wp[((4 + h) * 2 + 0) * 64 + l];
    const bf16x8 kA1 = wp[((4 + h) * 2 + 1) * 64 + l];
    f32x4 q[3], k[3];
#pragma unroll
    for (int b = 0; b < 3; ++b) {
      q[b] = __builtin_amdgcn_mfma_f32_16x16x32_bf16(qA0, Xf[b][0], zz, 0, 0, 0);
      q[b] = __builtin_amdgcn_mfma_f32_16x16x32_bf16(qA1, Xf[b][1], q[b], 0, 0, 0);
      k[b] = __builtin_amdgcn_mfma_f32_16x16x32_bf16(kA0, Xf[b][0], zz, 0, 0, 0);
      k[b] = __builtin_amdgcn_mfma_f32_16x16x32_bf16(kA1, Xf[b][1], k[b], 0, 0, 0);
    }
    // scores + softmax (reduce over the 4-lane row-groups)
    float P[3][3];
#pragma unroll
    for (int r1 = 0; r1 < 3; ++r1) {
      float sc[3];
#pragma unroll
      for (int r2 = 0; r2 < 3; ++r2) {
        float d = q[r1][0] * k[r2][0] + q[r1][1] * k[r2][1] +
                  q[r1][2] * k[r2][2] + q[r1][3] * k[r2][3];
        d += __shfl_xor(d, 16);
        d += __shfl_xor(d, 32);
        sc[r2] = d * 0.25f;
      }
      const float mx = fmaxf(sc[0], fmaxf(sc[1], sc[2]));
      const float e0 = __expf(sc[0] - mx);
      const float e1 = __expf(sc[1] - mx);
      const float e2 = __expf(sc[2] - mx);
      const float inv = 1.f / (e0 + e1 + e2);
      P[r1][0] = e0 * inv;
      P[r1][1] = e1 * inv;
      P[r1][2] = e2 * inv;
    }
    // v
    const bf16x8 vA0 = wp[((8 + h) * 2 + 0) * 64 + l];
    const bf16x8 vA1 = wp[((8 + h) * 2 + 1) * 64 + l];
    f32x4 v[3];
#pragma unroll
    for (int b = 0; b < 3; ++b) {
      v[b] = __builtin_amdgcn_mfma_f32_16x16x32_bf16(vA0, Xf[b][0], zz, 0, 0, 0);
      v[b] = __builtin_amdgcn_mfma_f32_16x16x32_bf16(vA1, Xf[b][1], v[b], 0, 0, 0);
    }
    // y = P @ v, write to LDS in proj-B-frag layout.
    const int sp = h >> 1;
    const int gp = (h & 1) * 2 + (g >> 1);
    const int wslot = (gp * 16 + c) * 16 + (g & 1) * 8;
#pragma unroll
    for (int r1 = 0; r1 < 3; ++r1) {
      float y0 = P[r1][0] * v[0][0] + P[r1][1] * v[1][0] + P[r1][2] * v[2][0];
      float y1 = P[r1][0] * v[0][1] + P[r1][1] * v[1][1] + P[r1][2] * v[2][1];
      float y2 = P[r1][0] * v[0][2] + P[r1][1] * v[1][2] + P[r1][2] * v[2][2];
      float y3 = P[r1][0] * v[0][3] + P[r1][1] * v[1][3] + P[r1][2] * v[2][3];
      uint2 pk;
      pk.x = (unsigned)f2bf(y0) | ((unsigned)f2bf(y1) << 16);
      pk.y = (unsigned)f2bf(y2) | ((unsigned)f2bf(y3) << 16);
      *(uint2*)(yBase + (r1 * 2 + sp) * 1024 + wslot) = pk;
    }
  }

  // ---------- epilogue: proj + residual-from-Xf ----------
  float bias_[4][4];
#pragma unroll
  for (int m = 0; m < 4; ++m) {
    const float4 bj = *(const float4*)(bproj + m * 16 + g * 4);
    bias_[m][0] = bj.x;
    bias_[m][1] = bj.y;
    bias_[m][2] = bj.z;
    bias_[m][3] = bj.w;
  }

#pragma unroll
  for (int b = 0; b < 3; ++b) {
    const bf16x8 yB0 = *(bf16x8*)(yBase + (b * 2 + 0) * 1024 + l * 16);
    const bf16x8 yB1 = *(bf16x8*)(yBase + (b * 2 + 1) * 1024 + l * 16);
#pragma unroll
    for (int m = 0; m < 4; ++m) {
      const bf16x8 pA0 = wp[(24 + m * 2 + 0) * 64 + l];
      const bf16x8 pA1 = wp[(24 + m * 2 + 1) * 64 + l];
      f32x4 o = __builtin_amdgcn_mfma_f32_16x16x32_bf16(pA0, yB0, zz, 0, 0, 0);
      o = __builtin_amdgcn_mfma_f32_16x16x32_bf16(pA1, yB1, o, 0, 0, 0);

      // residual from Xf via wave shuffles (all transient)
      union {
        bf16x8 v;
        unsigned u[4];
      } su;
      su.v = Xf[b][m >> 1];
      const int hl = ((m & 1) * 2 + (g >> 1)) * 16 + c;
      const unsigned w0 = (unsigned)__shfl((int)su.u[0], hl, 64);
      const unsigned w1 = (unsigned)__shfl((int)su.u[1], hl, 64);
      const unsigned w2 = (unsigned)__shfl((int)su.u[2], hl, 64);
      const unsigned w3 = (unsigned)__shfl((int)su.u[3], hl, 64);
      const unsigned lo = (g & 1) ? w2 : w0;  // channels j=0,1
      const unsigned hi = (g & 1) ? w3 : w1;  // channels j=2,3
      float res[4];
      res[0] = __uint_as_float(lo << 16);
      res[1] = __uint_as_float(lo & 0xffff0000u);
      res[2] = __uint_as_float(hi << 16);
      res[3] = __uint_as_float(hi & 0xffff0000u);

#pragma unroll
      for (int j = 0; j < 4; ++j) {
        outp[(b * 64 + m * 16 + g * 4 + j) * kHW] =
            fmaf(rv, o[j] + bias_[m][j], res[j]);
      }
    }
  }
}

extern "C" void kernel_launch(void* const* d_in, const int* in_sizes, int n_in,
                              void* d_out, int out_size, void* d_ws,
                              size_t ws_size, hipStream_t stream) {
  const float* hf = (const float*)d_in[0];
  const float* Wqkv = (const float*)d_in[1];
  const float* Wproj = (const float*)d_in[2];
  const float* bproj = (const float*)d_in[3];
  const float* rscale = (const float*)d_in[4];
  float* out = (float*)d_out;
  unsigned char* wsc = (unsigned char*)d_ws;

  hipLaunchKernelGGL(pack_weights, dim3(1), dim3(256), 0, stream, Wqkv, Wproj,
                     wsc);

  const int npix = in_sizes[0] / kC;  // 131072
  const int nblocks = npix / 64;      // 2048
  hipLaunchKernelGGL(hfattn_mfma8, dim3(nblocks), dim3(256), 0, stream, hf, wsc,
                     bproj, rscale, out);
}